// Round 10
// baseline (159.508 us; speedup 1.0000x reference)
//
#include <hip/hip_runtime.h>
#include <math.h>

#define T_STEPS 730
#define NB      1000
#define LENF    15
#define NEARZ   1e-5f
#define CHUNK   8       // 3-chunk rotation = 24 steps (= 0 mod 8, keeps phases static)
#define TPAD    736     // plane stride: 730 rounded to x16B; imm offsets <= 2944B < 4KB

// ---------------------------------------------------------------------------
// DPP helpers. Butterfly stages: quad_perm xor1 (0xB1), quad_perm xor2 (0x4E),
// row_half_mirror (0x141). Used STAGE-MAJOR across the 5 quantities so each
// stage's 5 independent ops cover the previous stage's latency (no hazard nops).
// ---------------------------------------------------------------------------
template <int CTRL>
__device__ __forceinline__ float dpp_mov(float x) {
    int xi = __builtin_bit_cast(int, x);
    int r  = __builtin_amdgcn_update_dpp(0, xi, CTRL, 0xF, 0xF, true);
    return __builtin_bit_cast(float, r);
}

// One step. T = runtime step index (addresses), K = compile-time phase 0..7
// (register indices / store schedule). Stores: lanes m0/m1 batch qs/qg sums
// into vq[8], dwordx4 every 4 steps (reuse distance 5 steps > store latency);
// lane m2 stores ch3..5 as one float3. No dummy stores.
#define STEP(CURV, T, K)                                                       \
  {                                                                            \
    float pcp = (CURV).x, pet = (CURV).y;                                      \
    float W     = pcp + S;                                                     \
    float term  = fmaf(W, inv2a, pb2a);                                        \
    float disc  = fmaf(term, term, -(W * boa));                                \
    float r     = __builtin_amdgcn_sqrtf(fmaxf(disc, NEARZ));                  \
    float Y     = term - r;                                                    \
    float e     = __builtin_amdgcn_exp2f(pet * ninvbl2);                       \
    float Sn    = Y * e;                                                       \
    float aet   = Y - Sn;                                                      \
    float avail = W - Y;                                                       \
    float Qs    = omc * avail;                                                 \
    float Gn    = fmaf(pc, avail, G) * inv1pd;                                 \
    float Qg    = pd * Gn;                                                     \
    S = Sn; G = Gn;                                                            \
    float q1 = Qs  + dpp_mov<0xB1>(Qs);                                        \
    float g1 = Qg  + dpp_mov<0xB1>(Qg);                                        \
    float a1 = aet + dpp_mov<0xB1>(aet);                                       \
    float s1 = Sn  + dpp_mov<0xB1>(Sn);                                        \
    float w1 = Gn  + dpp_mov<0xB1>(Gn);                                        \
    float q2 = q1 + dpp_mov<0x4E>(q1);                                         \
    float g2 = g1 + dpp_mov<0x4E>(g1);                                         \
    float a2 = a1 + dpp_mov<0x4E>(a1);                                         \
    float s2 = s1 + dpp_mov<0x4E>(s1);                                         \
    float w2 = w1 + dpp_mov<0x4E>(w1);                                         \
    float q3 = q2 + dpp_mov<0x141>(q2);                                        \
    float g3 = g2 + dpp_mov<0x141>(g2);                                        \
    float a3 = a2 + dpp_mov<0x141>(a2);                                        \
    float s3 = s2 + dpp_mov<0x141>(s2);                                        \
    float w3 = w2 + dpp_mov<0x141>(w2);                                        \
    vq[(K)] = (m == 0) ? q3 : g3;      /* 0.125 & UH norm folded into conv */  \
    if (m == 2) {                                                              \
        float* o3 = out + ((size_t)(T) * NB + b) * 6 + 3;                      \
        *(float3*)o3 = make_float3(a3 * 0.125f, s3 * 0.125f, w3 * 0.125f);     \
    }                                                                          \
    if ((K) == 3 && m < 2)                                                     \
        *(float4*)(qbase + ((T) - 3)) = make_float4(vq[0], vq[1], vq[2], vq[3]); \
    if ((K) == 7 && m < 2)                                                     \
        *(float4*)(qbase + ((T) - 7) + 4) = make_float4(vq[4], vq[5], vq[6], vq[7]); \
  }

// ---------------------------------------------------------------------------
// k1: the serial scan. Block = 64 = 1 wave = 8 basins x 8 members; grid 125.
// x via A/B/C triple-buffered 8-step chunks, prefetched 2 chunks (16 steps,
// ~1700 cyc) ahead, pinned by sched_barrier(0) (proven R6/R8).
// ---------------------------------------------------------------------------
__global__ __launch_bounds__(64, 1) void scan_kernel(const float* __restrict__ x,
                                                     const float* __restrict__ raw,
                                                     float* __restrict__ out,
                                                     float* __restrict__ qsp,
                                                     float* __restrict__ qgp) {
    const int L  = threadIdx.x;
    const int lb = L >> 3;                 // local basin 0..7
    const int m  = L & 7;                  // member / role
    const int b  = blockIdx.x * 8 + lb;    // global basin

    // raw layout (B,34) = [a(8), b(8), c(8), d(8), ra, rb]
    const float* rp = raw + b * 34;
    float pa = rp[0 * 8 + m] * 0.9f + 0.1f;
    float pb = rp[1 * 8 + m] * 450.0f + 50.0f;
    float pc = rp[2 * 8 + m];
    float pd = rp[3 * 8 + m] * 0.89f + 0.01f;

    float inv2a   = 1.0f / (2.0f * pa);
    float pb2a    = pb * inv2a;
    float boa     = pb / pa;
    float ninvbl2 = -1.4426950408889634f / pb;   // exp(-pet/b)=exp2(pet*this)
    float omc     = 1.0f - pc;
    float inv1pd  = 1.0f / (1.0f + pd);

    // per-lane batched-store base: m0 -> qs plane, m1 -> qg plane (layout
    // [b][TPAD]); other lanes masked off at the store, pointer unused.
    float* qbase = ((m == 1) ? qgp : qsp) + b * TPAD;

    float S = 50.0f, G = 10.0f;
    float vq[8];
#pragma unroll
    for (int k = 0; k < 8; ++k) vq[k] = 0.0f;

    const float2* __restrict__ xf = (const float2*)x;   // (T,B) of (p,pet)

    float2 A[CHUNK], B[CHUNK], C[CHUNK];
#pragma unroll
    for (int j = 0; j < CHUNK; ++j) A[j] = xf[(0 * CHUNK + j) * NB + b];
#pragma unroll
    for (int j = 0; j < CHUNK; ++j) B[j] = xf[(1 * CHUNK + j) * NB + b];

    // 30 groups x 3 chunks (24 steps each; 24 % 8 == 0 so K-phase is static)
    for (int cg = 0; cg < 30; ++cg) {
        const int c0 = 3 * cg;
        const int tb = 24 * cg;
        // phase 0: consume A (chunk c0), prefetch chunk c0+2 -> C
#pragma unroll
        for (int j = 0; j < CHUNK; ++j) C[j] = xf[((c0 + 2) * CHUNK + j) * NB + b];
        __builtin_amdgcn_sched_barrier(0);
#pragma unroll
        for (int j = 0; j < CHUNK; ++j) STEP(A[j], tb + j, j);
        // phase 1: consume B (chunk c0+1), prefetch chunk c0+3 -> A
#pragma unroll
        for (int j = 0; j < CHUNK; ++j) A[j] = xf[((c0 + 3) * CHUNK + j) * NB + b];
        __builtin_amdgcn_sched_barrier(0);
#pragma unroll
        for (int j = 0; j < CHUNK; ++j) STEP(B[j], tb + 8 + j, j);
        // phase 2: consume C (chunk c0+2), prefetch chunk c0+4 -> B (clamped:
        // chunk 91 covers t=728..735; t>=730 clamps to 729, harmless)
#pragma unroll
        for (int j = 0; j < CHUNK; ++j) {
            int tt = (c0 + 4) * CHUNK + j;
            tt = tt < T_STEPS ? tt : (T_STEPS - 1);
            B[j] = xf[tt * NB + b];
        }
        __builtin_amdgcn_sched_barrier(0);
#pragma unroll
        for (int j = 0; j < CHUNK; ++j) STEP(C[j], tb + 16 + j, j);
    }
    // tail: chunk 90 (t=720..727) in A; t=728,729 are B[0],B[1] (clamped chunk 91)
#pragma unroll
    for (int j = 0; j < CHUNK; ++j) STEP(A[j], 720 + j, j);
    STEP(B[0], 728, 0);
    STEP(B[1], 729, 1);
    if (m < 2) *(float2*)(qbase + 728) = make_float2(vq[0], vq[1]);
}

// ---------------------------------------------------------------------------
// k2: gamma-UH 15-tap causal conv, UH computed inline (gammaln cancels under
// normalization; 0.125 ensemble mean folded into weights). Lane = t -> plane
// reads coalesced. Writes out ch0..2 (ch0 = ch1 + ch2 by linearity).
// ---------------------------------------------------------------------------
__global__ __launch_bounds__(256) void conv_kernel(const float* __restrict__ qsp,
                                                   const float* __restrict__ qgp,
                                                   const float* __restrict__ raw,
                                                   float* __restrict__ out) {
    const int b = blockIdx.y;
    const int t = blockIdx.x * 256 + threadIdx.x;

    float ra = raw[b * 34 + 32] * 2.9f;
    float rb = raw[b * 34 + 33] * 6.5f;
    float aa = fmaxf(ra, 0.0f) + 0.1f;
    float th = fmaxf(rb, 0.0f) + 0.5f;
    float inv_th = 1.0f / th;
    float am1 = aa - 1.0f;
    float w[LENF];
    float sw = 0.0f;
#pragma unroll
    for (int k = 0; k < LENF; ++k) {
        float tt = (float)k + 0.5f;
        w[k] = __expf(am1 * __logf(tt) - tt * inv_th);
        sw += w[k];
    }
    float invs = 0.125f / sw;        // UH normalization x ensemble mean
#pragma unroll
    for (int k = 0; k < LENF; ++k) w[k] *= invs;

    if (t >= T_STEPS) return;
    const float* qs = qsp + b * TPAD;
    const float* qg = qgp + b * TPAD;
    float ys = 0.0f, yg = 0.0f;
    int kmax = t < (LENF - 1) ? t : (LENF - 1);
    for (int k = 0; k <= kmax; ++k) {
        ys = fmaf(qs[t - k], w[k], ys);
        yg = fmaf(qg[t - k], w[k], yg);
    }
    float* o = out + ((size_t)t * NB + b) * 6;
    o[0] = ys + yg;
    o[1] = ys;
    o[2] = yg;
}

// ---------------------------------------------------------------------------
extern "C" void kernel_launch(void* const* d_in, const int* in_sizes, int n_in,
                              void* d_out, int out_size, void* d_ws, size_t ws_size,
                              hipStream_t stream) {
    const float* x   = (const float*)d_in[0];   // (T,B,2) fp32
    const float* raw = (const float*)d_in[1];   // (B,34)  fp32
    float* out = (float*)d_out;                 // (T,B,6) fp32

    // ws (floats): qs plane [NB][TPAD] | qg plane [NB][TPAD]  = 5.89 MB
    float* qsp = (float*)d_ws;
    float* qgp = qsp + (size_t)NB * TPAD;

    scan_kernel<<<dim3(NB / 8),      dim3(64),  0, stream>>>(x, raw, out, qsp, qgp);
    conv_kernel<<<dim3(3, NB),       dim3(256), 0, stream>>>(qsp, qgp, raw, out);
}

// Round 11
// 150.250 us; speedup vs baseline: 1.0616x; 1.0616x over previous
//
#include <hip/hip_runtime.h>
#include <math.h>

#define T_STEPS 730
#define NB      1000
#define LENF    15
#define NEARZ   1e-5f
#define CHUNK   10      // 730 = 73 chunks of 10 (R8-proven prefetch shape)
#define WND     120     // LDS window steps = 12 chunks; 730 = 6*120 + 10

// ---------------------------------------------------------------------------
// DPP helpers. Butterfly stages: quad_perm xor1 (0xB1), quad_perm xor2 (0x4E),
// row_half_mirror (0x141). Stage-major across the 5 quantities so each
// stage's 5 independent ops cover the previous stage's latency.
// ---------------------------------------------------------------------------
template <int CTRL>
__device__ __forceinline__ float dpp_mov(float x) {
    int xi = __builtin_bit_cast(int, x);
    int r  = __builtin_amdgcn_update_dpp(0, xi, CTRL, 0xF, 0xF, true);
    return __builtin_bit_cast(float, r);
}

// One step. TL = compile-time t_loc within the LDS window. Ends in ONE
// branchless ds_write (lanes m>=5 write into their own garbage slots).
// NO global ops: keeps the vmcnt FIFO pure prefetch-loads (R9 post-mortem).
#define STEP(CURV, TL)                                                         \
  {                                                                            \
    float pcp = (CURV).x, pet = (CURV).y;                                      \
    float W     = pcp + S;                                                     \
    float term  = fmaf(W, inv2a, pb2a);                                        \
    float disc  = fmaf(term, term, -(W * boa));                                \
    float r     = __builtin_amdgcn_sqrtf(fmaxf(disc, NEARZ));                  \
    float Y     = term - r;                                                    \
    float e     = __builtin_amdgcn_exp2f(pet * ninvbl2);                       \
    float Sn    = Y * e;                                                       \
    float aet   = Y - Sn;                                                      \
    float avail = W - Y;                                                       \
    float Qs    = omc * avail;                                                 \
    float Gn    = fmaf(pc, avail, G) * inv1pd;                                 \
    float Qg    = pd * Gn;                                                     \
    S = Sn; G = Gn;                                                            \
    float q1 = Qs  + dpp_mov<0xB1>(Qs);                                        \
    float g1 = Qg  + dpp_mov<0xB1>(Qg);                                        \
    float a1 = aet + dpp_mov<0xB1>(aet);                                       \
    float s1 = Sn  + dpp_mov<0xB1>(Sn);                                        \
    float w1 = Gn  + dpp_mov<0xB1>(Gn);                                        \
    float q2 = q1 + dpp_mov<0x4E>(q1);                                         \
    float g2 = g1 + dpp_mov<0x4E>(g1);                                         \
    float a2 = a1 + dpp_mov<0x4E>(a1);                                         \
    float s2 = s1 + dpp_mov<0x4E>(s1);                                         \
    float w2 = w1 + dpp_mov<0x4E>(w1);                                         \
    float q3 = q2 + dpp_mov<0x141>(q2);                                        \
    float g3 = g2 + dpp_mov<0x141>(g2);                                        \
    float a3 = a2 + dpp_mov<0x141>(a2);                                        \
    float s3 = s2 + dpp_mov<0x141>(s2);                                        \
    float w3 = w2 + dpp_mov<0x141>(w2);                                        \
    float v = q3;                      /* loop-invariant cmps -> LICM'd sgpr */\
    v = (m == 1) ? g3 : v;                                                     \
    v = (m == 2) ? a3 : v;                                                     \
    v = (m == 3) ? s3 : v;                                                     \
    v = (m == 4) ? w3 : v;                                                     \
    sh[(TL) * 64 + perm] = v;                                                  \
  }

// ---------------------------------------------------------------------------
// k1: the serial scan. Block = 64 = 1 wave = 8 basins x 8 members; grid 125.
// x via A/B/C triple-buffered 10-step chunks prefetched 2 chunks ahead,
// pinned by sched_barrier(0) (R8-proven). Results go to a 120-step LDS
// window; after each window a branchless flush (lane = (quantity,basin))
// does ds_read + one global store per t. Single wave -> lgkmcnt ordering,
// no barrier needed (R7-proven).
// ---------------------------------------------------------------------------
__global__ __launch_bounds__(64, 1) void scan_kernel(const float* __restrict__ x,
                                                     const float* __restrict__ raw,
                                                     float* __restrict__ out,
                                                     float* __restrict__ qsp,
                                                     float* __restrict__ qgp,
                                                     float* __restrict__ dummy) {
    __shared__ float sh[WND * 64];         // [t_loc][slot], 30720 B

    const int L  = threadIdx.x;
    const int lb = L >> 3;                 // local basin 0..7 (scan role)
    const int m  = L & 7;                  // member / quantity (scan role)
    const int b  = blockIdx.x * 8 + lb;    // global basin
    const int perm = ((L & 7) << 3) | (L >> 3);   // scan write slot m*8+lb

    // raw layout (B,34) = [a(8), b(8), c(8), d(8), ra, rb]
    const float* rp = raw + b * 34;
    float pa = rp[0 * 8 + m] * 0.9f + 0.1f;
    float pb = rp[1 * 8 + m] * 450.0f + 50.0f;
    float pc = rp[2 * 8 + m];
    float pd = rp[3 * 8 + m] * 0.89f + 0.01f;

    float inv2a   = 1.0f / (2.0f * pa);
    float pb2a    = pb * inv2a;
    float boa     = pb / pa;
    float ninvbl2 = -1.4426950408889634f / pb;   // exp(-pet/b)=exp2(pet*this)
    float omc     = 1.0f - pc;
    float inv1pd  = 1.0f / (1.0f + pd);

    // flush role: lane L <-> (quantity mq, basin lbq); one store stream each.
    const int mq  = L >> 3;
    const int lbq = L & 7;
    const int gb  = blockIdx.x * 8 + lbq;
    float* fptr;
    int    fstride;                        // bytes per t
    float  fscale;
    if      (mq == 0) { fptr = qsp + gb;                    fstride = NB * 4;     fscale = 1.0f;   }
    else if (mq == 1) { fptr = qgp + gb;                    fstride = NB * 4;     fscale = 1.0f;   }
    else if (mq <= 4) { fptr = out + (size_t)gb * 6 + mq + 1; fstride = NB * 24;  fscale = 0.125f; }
    else              { fptr = dummy + (blockIdx.x * 64 + L); fstride = 0;        fscale = 1.0f;   }

    float S = 50.0f, G = 10.0f;

    const float2* __restrict__ xf = (const float2*)x;   // (T,B) of (p,pet)

    float2 A[CHUNK], B[CHUNK], C[CHUNK];
#pragma unroll
    for (int j = 0; j < CHUNK; ++j) A[j] = xf[(0 * CHUNK + j) * NB + b];
#pragma unroll
    for (int j = 0; j < CHUNK; ++j) B[j] = xf[(1 * CHUNK + j) * NB + b];

    // 6 windows x (4 chunk-groups x 3 chunks = 120 steps) + flush each
    for (int w = 0; w < 6; ++w) {
#pragma unroll
        for (int g = 0; g < 4; ++g) {
            const int c0 = (w * 4 + g) * 3;
            // phase 0: consume A (chunk c0), prefetch chunk c0+2 -> C
#pragma unroll
            for (int j = 0; j < CHUNK; ++j) C[j] = xf[((c0 + 2) * CHUNK + j) * NB + b];
            __builtin_amdgcn_sched_barrier(0);
#pragma unroll
            for (int j = 0; j < CHUNK; ++j) STEP(A[j], g * 30 + j);
            // phase 1: consume B (chunk c0+1), prefetch chunk c0+3 -> A
#pragma unroll
            for (int j = 0; j < CHUNK; ++j) A[j] = xf[((c0 + 3) * CHUNK + j) * NB + b];
            __builtin_amdgcn_sched_barrier(0);
#pragma unroll
            for (int j = 0; j < CHUNK; ++j) STEP(B[j], g * 30 + 10 + j);
            // phase 2: consume C (chunk c0+2), prefetch chunk c0+4 -> B (clamped)
#pragma unroll
            for (int j = 0; j < CHUNK; ++j) {
                int tt = (c0 + 4) * CHUNK + j;
                tt = tt < T_STEPS ? tt : (T_STEPS - 1);
                B[j] = xf[tt * NB + b];
            }
            __builtin_amdgcn_sched_barrier(0);
#pragma unroll
            for (int j = 0; j < CHUNK; ++j) STEP(C[j], g * 30 + 20 + j);
        }
        // flush window w (120 t-values); fresh store-data regs, no reuse hazard
#pragma unroll 4
        for (int i = 0; i < WND; ++i) {
            float v = sh[i * 64 + L];
            *fptr = v * fscale;
            fptr = (float*)((char*)fptr + fstride);
        }
    }
    // tail: chunk 72 (t=720..729) resident in A
#pragma unroll
    for (int j = 0; j < CHUNK; ++j) STEP(A[j], j);
#pragma unroll
    for (int i = 0; i < 10; ++i) {
        float v = sh[i * 64 + L];
        *fptr = v * fscale;
        fptr = (float*)((char*)fptr + fstride);
    }
}

// ---------------------------------------------------------------------------
// k0: gamma unit hydrograph, transposed layout UH_T[k*NB + b]. gammaln and
// aa*log(theta) cancel under normalization. 0.125 ensemble mean folded in.
// ---------------------------------------------------------------------------
__global__ __launch_bounds__(256) void uh_kernel(const float* __restrict__ raw,
                                                 float* __restrict__ uh) {
    int b = blockIdx.x * 256 + threadIdx.x;
    if (b >= NB) return;
    float ra = raw[b * 34 + 32] * 2.9f;
    float rb = raw[b * 34 + 33] * 6.5f;
    float aa = fmaxf(ra, 0.0f) + 0.1f;
    float th = fmaxf(rb, 0.0f) + 0.5f;
    float inv_th = 1.0f / th;
    float am1 = aa - 1.0f;
    float w[LENF];
    float s = 0.0f;
#pragma unroll
    for (int k = 0; k < LENF; ++k) {
        float t = (float)k + 0.5f;
        float lw = am1 * __logf(t) - t * inv_th;
        w[k] = __expf(lw);
        s += w[k];
    }
    float invs = 0.125f / s;               // UH norm x ensemble mean
#pragma unroll
    for (int k = 0; k < LENF; ++k) uh[k * NB + b] = w[k] * invs;
}

// ---------------------------------------------------------------------------
// k2: 15-tap causal convolution per (t, basin); writes out ch0..2.
// ch0 = ch1 + ch2 by linearity. (R1/R8-proven kernel.)
// ---------------------------------------------------------------------------
__global__ __launch_bounds__(256) void conv_kernel(const float* __restrict__ qs_ws,
                                                   const float* __restrict__ qg_ws,
                                                   const float* __restrict__ uh,
                                                   float* __restrict__ out) {
    int b = blockIdx.x * 256 + threadIdx.x;
    int t = blockIdx.y;
    if (b >= NB) return;
    float ys = 0.0f, yg = 0.0f;
    int kmax = t < (LENF - 1) ? t : (LENF - 1);
    for (int k = 0; k <= kmax; ++k) {
        float w = uh[k * NB + b];
        ys = fmaf(qs_ws[(t - k) * NB + b], w, ys);
        yg = fmaf(qg_ws[(t - k) * NB + b], w, yg);
    }
    float* o = out + (t * NB + b) * 6;
    o[0] = ys + yg;
    o[1] = ys;
    o[2] = yg;
}

// ---------------------------------------------------------------------------
extern "C" void kernel_launch(void* const* d_in, const int* in_sizes, int n_in,
                              void* d_out, int out_size, void* d_ws, size_t ws_size,
                              hipStream_t stream) {
    const float* x   = (const float*)d_in[0];   // (T,B,2) fp32
    const float* raw = (const float*)d_in[1];   // (B,34)  fp32
    float* out = (float*)d_out;                 // (T,B,6) fp32

    // ws (floats): qs[730000] | qg[730000] | uh[15000] | dummy[8000] = 5.9 MB
    float* qs = (float*)d_ws;
    float* qg = qs + (size_t)T_STEPS * NB;
    float* uh = qg + (size_t)T_STEPS * NB;
    float* dm = uh + (size_t)LENF * NB;

    uh_kernel  <<<dim3((NB + 255) / 256),          dim3(256), 0, stream>>>(raw, uh);
    scan_kernel<<<dim3(NB / 8),                    dim3(64),  0, stream>>>(x, raw, out, qs, qg, dm);
    conv_kernel<<<dim3((NB + 255) / 256, T_STEPS), dim3(256), 0, stream>>>(qs, qg, uh, out);
}

// Round 12
// 126.721 us; speedup vs baseline: 1.2587x; 1.1857x over previous
//
#include <hip/hip_runtime.h>
#include <math.h>

#define T_STEPS 730
#define NB      1000
#define LENF    15
#define NEARZ   1e-5f
#define TPAD    736            // per-lane row stride (floats); 730 rounded to x16B
#define NLANES  8000           // 1000 basins x 8 members

// ===========================================================================
// PASS A: serial S/G state recurrence only (R10 post-mortem: R8's loop was
// ~70% issue-bound; the DPP reduction tree + selects were ~60% of the issued
// instructions -> move everything t-parallel to pass B).
// Per step: 13 VALU physics + 0.5 store + ~1 prefetch addr.
// Stores: 16-deep register rings, dwordx4 every 4 steps, per-lane rows with
// compile-time byte offsets (reuse distance 13 steps ~ 500cyc: no vmcnt
// stall on data-reg reuse).
// ===========================================================================
#define STEPA(CURV, Q, SIDX)                                                   \
  {                                                                            \
    float pcp = (CURV).x, pet = (CURV).y;                                      \
    float W     = pcp + S;                                                     \
    float term  = fmaf(W, inv2a, pb2a);                                        \
    float disc  = fmaf(term, term, -(W * boa));                                \
    float r     = __builtin_amdgcn_sqrtf(fmaxf(disc, NEARZ));                  \
    float Y     = term - r;                                                    \
    float e     = __builtin_amdgcn_exp2f(pet * ninvbl2);                       \
    float Sn    = Y * e;                                                       \
    float avail = W - Y;                                                       \
    float Gn    = fmaf(pc, avail, G) * inv1pd;                                 \
    S = Sn; G = Gn;                                                            \
    sr[(Q)] = Sn;                                                              \
    gr[(Q)] = Gn;                                                              \
    if (((Q) & 3) == 3) {                                                      \
      *(float4*)(pS + (SIDX) - 3) =                                            \
          make_float4(sr[(Q) - 3], sr[(Q) - 2], sr[(Q) - 1], sr[(Q)]);         \
      *(float4*)(pG + (SIDX) - 3) =                                            \
          make_float4(gr[(Q) - 3], gr[(Q) - 2], gr[(Q) - 1], gr[(Q)]);         \
    }                                                                          \
  }

#define PREFETCH(BUF, CI)                                                      \
  _Pragma("unroll")                                                            \
  for (int j = 0; j < 8; ++j) {                                                \
      int tt = (CI) * 8 + j;                                                   \
      tt = tt < T_STEPS ? tt : (T_STEPS - 1);                                  \
      BUF[j] = xf[tt * NB + b];                                                \
  }                                                                            \
  __builtin_amdgcn_sched_barrier(0);

__global__ __launch_bounds__(64, 1) void scan_state(const float* __restrict__ x,
                                                    const float* __restrict__ raw,
                                                    float* __restrict__ snp,
                                                    float* __restrict__ gnp) {
    const int L   = threadIdx.x;
    const int gid = blockIdx.x * 64 + L;   // 0..7999 (grid=125)
    const int b   = gid >> 3;
    const int m   = gid & 7;

    // raw layout (B,34) = [a(8), b(8), c(8), d(8), ra, rb]
    const float* rp = raw + b * 34;
    float pa = rp[0 * 8 + m] * 0.9f + 0.1f;
    float pb = rp[1 * 8 + m] * 450.0f + 50.0f;
    float pc = rp[2 * 8 + m];
    float pd = rp[3 * 8 + m] * 0.89f + 0.01f;

    float inv2a   = 1.0f / (2.0f * pa);
    float pb2a    = pb * inv2a;
    float boa     = pb / pa;
    float ninvbl2 = -1.4426950408889634f / pb;   // exp(-pet/b)=exp2(pet*this)
    float inv1pd  = 1.0f / (1.0f + pd);

    float* pS = snp + (size_t)gid * TPAD;  // 16B-aligned (736*4 % 16 == 0)
    float* pG = gnp + (size_t)gid * TPAD;

    float S = 50.0f, G = 10.0f;
    float sr[16], gr[16];

    const float2* __restrict__ xf = (const float2*)x;   // (T,B) of (p,pet)

    float2 A[8], Bb[8], Cc[8];
    PREFETCH(A, 0)
    PREFETCH(Bb, 1)

    // 15 groups x 48 steps (6 chunks of 8; 48 % 16 == 0 keeps ring phase
    // static across groups) = 720 steps, + 10-step tail.
    for (int g = 0; g < 15; ++g) {
        const int c0 = 6 * g;
        PREFETCH(Cc, c0 + 2)
#pragma unroll
        for (int j = 0; j < 8; ++j) STEPA(A[j],  j,      j)
        PREFETCH(A, c0 + 3)
#pragma unroll
        for (int j = 0; j < 8; ++j) STEPA(Bb[j], 8 + j,  8 + j)
        PREFETCH(Bb, c0 + 4)
#pragma unroll
        for (int j = 0; j < 8; ++j) STEPA(Cc[j], j,      16 + j)
        PREFETCH(Cc, c0 + 5)
#pragma unroll
        for (int j = 0; j < 8; ++j) STEPA(A[j],  8 + j,  24 + j)
        PREFETCH(A, c0 + 6)
#pragma unroll
        for (int j = 0; j < 8; ++j) STEPA(Bb[j], j,      32 + j)
        PREFETCH(Bb, c0 + 7)
#pragma unroll
        for (int j = 0; j < 8; ++j) STEPA(Cc[j], 8 + j,  40 + j)
        pS += 48; pG += 48;
    }
    // tail: A = chunk 90 (t=720..727), B = clamped chunk 91 (B[0]=728, B[1]=729)
#pragma unroll
    for (int j = 0; j < 8; ++j) STEPA(A[j], j, j)
    STEPA(Bb[0], 8, 8)
    STEPA(Bb[1], 9, 9)
    *(float2*)(pS + 8) = make_float2(sr[8], sr[9]);
    *(float2*)(pG + 8) = make_float2(gr[8], gr[9]);
}

// ===========================================================================
// PASS B: t-parallel finalize. Block = 256 threads = one (t-tile, basin);
// grid = (3, 1000). Reconstructs Y = Sn*exp2(+pet/b) (exact inverse of pass
// A's factor), computes all 5 cross-member means, writes ch3..5, stages
// qs/qg sums in LDS (270 = 256 + 14 halo), then 15-tap gamma-UH conv
// (weights inline; 0.125 ensemble mean folded in) -> ch0..2.
// ===========================================================================
__global__ __launch_bounds__(256) void finalize(const float* __restrict__ x,
                                                const float* __restrict__ raw,
                                                const float* __restrict__ snp,
                                                const float* __restrict__ gnp,
                                                float* __restrict__ out) {
    __shared__ float qs_sh[270], qg_sh[270];

    const int b     = blockIdx.y;
    const int tbase = blockIdx.x * 256;
    const int tid   = threadIdx.x;

    // per-member derived params (block-uniform loads -> broadcast)
    const float* rp = raw + b * 34;
    float e2s[8], omc_[8], d_[8];
#pragma unroll
    for (int m = 0; m < 8; ++m) {
        float pb = rp[8 + m] * 450.0f + 50.0f;
        e2s[m]  = 1.4426950408889634f / pb;     // Y = Sn * exp2(pet * e2s)
        omc_[m] = 1.0f - rp[16 + m];
        d_[m]   = rp[24 + m] * 0.89f + 0.01f;
    }

    const float2* __restrict__ xf = (const float2*)x;

    // ---- compute phase: 270 t-values (tile + 14-step halo) ----------------
#pragma unroll
    for (int it = 0; it < 2; ++it) {
        int idx = tid + it * 256;
        if (idx < 270) {
            int tt = tbase + idx - 14;
            float qs = 0.0f, qg = 0.0f;
            if (tt >= 0 && tt < T_STEPS) {
                float2 pc2 = xf[tt * NB + b];
                float p = pc2.x, pet = pc2.y;
                float aet = 0.0f, ssum = 0.0f, gsum = 0.0f;
                int tprev = tt > 0 ? tt - 1 : 0;
#pragma unroll
                for (int m = 0; m < 8; ++m) {
                    const float* rowS = snp + (size_t)(b * 8 + m) * TPAD;
                    const float* rowG = gnp + (size_t)(b * 8 + m) * TPAD;
                    float sn = rowS[tt];
                    float sp = tt > 0 ? rowS[tprev] : 50.0f;
                    float gn = rowG[tt];
                    float y  = sn * __builtin_amdgcn_exp2f(pet * e2s[m]);
                    float avail = (p + sp) - y;
                    qs   += omc_[m] * avail;
                    qg   += d_[m] * gn;
                    aet  += y - sn;
                    ssum += sn;
                    gsum += gn;
                }
                if (idx >= 14) {   // own tile only (halo owned by prev block)
                    float* o = out + ((size_t)tt * NB + b) * 6;
                    o[3] = aet * 0.125f;
                    o[4] = ssum * 0.125f;
                    o[5] = gsum * 0.125f;
                }
            }
            qs_sh[idx] = qs;       // zero for tt<0 (block 0 halo) / tt>=T
            qg_sh[idx] = qg;
        }
    }
    __syncthreads();

    // ---- conv phase: gamma-UH weights (gammaln cancels under norm) --------
    const int t = tbase + tid;
    if (t >= T_STEPS) return;

    float ra = rp[32] * 2.9f;
    float rb = rp[33] * 6.5f;
    float aa = fmaxf(ra, 0.0f) + 0.1f;
    float th = fmaxf(rb, 0.0f) + 0.5f;
    float inv_th = 1.0f / th;
    float am1 = aa - 1.0f;
    float w[LENF];
    float sw = 0.0f;
#pragma unroll
    for (int k = 0; k < LENF; ++k) {
        float tk = (float)k + 0.5f;
        w[k] = __expf(am1 * __logf(tk) - tk * inv_th);
        sw += w[k];
    }
    float invs = 0.125f / sw;      // UH normalization x ensemble mean
    float ys = 0.0f, yg = 0.0f;
#pragma unroll
    for (int k = 0; k < LENF; ++k) {
        float wk = w[k] * invs;
        ys = fmaf(qs_sh[tid + 14 - k], wk, ys);
        yg = fmaf(qg_sh[tid + 14 - k], wk, yg);
    }
    float* o = out + ((size_t)t * NB + b) * 6;
    o[0] = ys + yg;
    o[1] = ys;
    o[2] = yg;
}

// ===========================================================================
// FALLBACK (ws too small for the 47MB state planes): R8's proven path.
// ===========================================================================
template <int CTRL>
__device__ __forceinline__ float dpp_mov(float x) {
    int xi = __builtin_bit_cast(int, x);
    int r  = __builtin_amdgcn_update_dpp(0, xi, CTRL, 0xF, 0xF, true);
    return __builtin_bit_cast(float, r);
}
__device__ __forceinline__ float sum8(float v) {
    v += dpp_mov<0xB1>(v);
    v += dpp_mov<0x4E>(v);
    v += dpp_mov<0x141>(v);
    return v;
}

#define STEPF(CURV)                                                            \
  {                                                                            \
    float pcp = (CURV).x, pet = (CURV).y;                                      \
    float W     = pcp + S;                                                     \
    float term  = fmaf(W, inv2a, pb2a);                                        \
    float disc  = fmaf(term, term, -(W * boa));                                \
    float r     = __builtin_amdgcn_sqrtf(fmaxf(disc, NEARZ));                  \
    float Y     = term - r;                                                    \
    float e     = __builtin_amdgcn_exp2f(pet * ninvbl2);                       \
    float Sn    = Y * e;                                                       \
    float AET   = Y - Sn;                                                      \
    float avail = W - Y;                                                       \
    float Qs    = omc * avail;                                                 \
    float Gn    = fmaf(pc, avail, G) * inv1pd;                                 \
    float Qg    = pd * Gn;                                                     \
    S = Sn; G = Gn;                                                            \
    float qs_s = sum8(Qs);                                                     \
    float qg_s = sum8(Qg);                                                     \
    float ae_s = sum8(AET);                                                    \
    float s_s  = sum8(Sn);                                                     \
    float g_s  = sum8(Gn);                                                     \
    float v = qs_s;                                                            \
    v = (m == 1) ? qg_s : v;                                                   \
    v = (m == 2) ? ae_s : v;                                                   \
    v = (m == 3) ? s_s  : v;                                                   \
    v = (m >= 4) ? g_s  : v;                                                   \
    *optr = v * 0.125f;                                                        \
    optr += incr;                                                              \
  }

__global__ __launch_bounds__(64, 1) void scan_fb(const float* __restrict__ x,
                                                 const float* __restrict__ raw,
                                                 float* __restrict__ out,
                                                 float* __restrict__ qs_ws,
                                                 float* __restrict__ qg_ws,
                                                 float* __restrict__ dummy) {
    const int L  = threadIdx.x;
    const int lb = L >> 3;
    const int m  = L & 7;
    const int b  = blockIdx.x * 8 + lb;

    const float* rp = raw + b * 34;
    float pa = rp[0 * 8 + m] * 0.9f + 0.1f;
    float pb = rp[1 * 8 + m] * 450.0f + 50.0f;
    float pc = rp[2 * 8 + m];
    float pd = rp[3 * 8 + m] * 0.89f + 0.01f;
    float inv2a   = 1.0f / (2.0f * pa);
    float pb2a    = pb * inv2a;
    float boa     = pb / pa;
    float ninvbl2 = -1.4426950408889634f / pb;
    float omc     = 1.0f - pc;
    float inv1pd  = 1.0f / (1.0f + pd);

    float* optr;
    long long incr;
    if      (m == 0) { optr = qs_ws + b;                      incr = NB;     }
    else if (m == 1) { optr = qg_ws + b;                      incr = NB;     }
    else if (m <= 4) { optr = out + (long long)b * 6 + m + 1; incr = NB * 6; }
    else             { optr = dummy + (blockIdx.x * 64 + L);  incr = 0;      }

    float S = 50.0f, G = 10.0f;
    const float2* __restrict__ xf = (const float2*)x;

    float2 A[10], B[10], C[10];
#pragma unroll
    for (int j = 0; j < 10; ++j) A[j] = xf[j * NB + b];
#pragma unroll
    for (int j = 0; j < 10; ++j) B[j] = xf[(10 + j) * NB + b];

    for (int cg = 0; cg < 24; ++cg) {
        const int c0 = 3 * cg;
#pragma unroll
        for (int j = 0; j < 10; ++j) C[j] = xf[((c0 + 2) * 10 + j) * NB + b];
        __builtin_amdgcn_sched_barrier(0);
#pragma unroll
        for (int j = 0; j < 10; ++j) STEPF(A[j]);
#pragma unroll
        for (int j = 0; j < 10; ++j) A[j] = xf[((c0 + 3) * 10 + j) * NB + b];
        __builtin_amdgcn_sched_barrier(0);
#pragma unroll
        for (int j = 0; j < 10; ++j) STEPF(B[j]);
#pragma unroll
        for (int j = 0; j < 10; ++j) {
            int t = (c0 + 4) * 10 + j;
            t = t < T_STEPS ? t : (T_STEPS - 1);
            B[j] = xf[t * NB + b];
        }
        __builtin_amdgcn_sched_barrier(0);
#pragma unroll
        for (int j = 0; j < 10; ++j) STEPF(C[j]);
    }
#pragma unroll
    for (int j = 0; j < 10; ++j) STEPF(A[j]);
}

__global__ __launch_bounds__(256) void uh_fb(const float* __restrict__ raw,
                                             float* __restrict__ uh) {
    int b = blockIdx.x * 256 + threadIdx.x;
    if (b >= NB) return;
    float ra = raw[b * 34 + 32] * 2.9f;
    float rb = raw[b * 34 + 33] * 6.5f;
    float aa = fmaxf(ra, 0.0f) + 0.1f;
    float th = fmaxf(rb, 0.0f) + 0.5f;
    float inv_th = 1.0f / th;
    float am1 = aa - 1.0f;
    float w[LENF];
    float s = 0.0f;
#pragma unroll
    for (int k = 0; k < LENF; ++k) {
        float t = (float)k + 0.5f;
        w[k] = __expf(am1 * __logf(t) - t * inv_th);
        s += w[k];
    }
    float invs = 1.0f / s;
#pragma unroll
    for (int k = 0; k < LENF; ++k) uh[k * NB + b] = w[k] * invs;
}

__global__ __launch_bounds__(256) void conv_fb(const float* __restrict__ qs_ws,
                                               const float* __restrict__ qg_ws,
                                               const float* __restrict__ uh,
                                               float* __restrict__ out) {
    int b = blockIdx.x * 256 + threadIdx.x;
    int t = blockIdx.y;
    if (b >= NB) return;
    float ys = 0.0f, yg = 0.0f;
    int kmax = t < (LENF - 1) ? t : (LENF - 1);
    for (int k = 0; k <= kmax; ++k) {
        float w = uh[k * NB + b];
        ys = fmaf(qs_ws[(t - k) * NB + b], w, ys);
        yg = fmaf(qg_ws[(t - k) * NB + b], w, yg);
    }
    float* o = out + (t * NB + b) * 6;
    o[0] = ys + yg;
    o[1] = ys;
    o[2] = yg;
}

// ===========================================================================
extern "C" void kernel_launch(void* const* d_in, const int* in_sizes, int n_in,
                              void* d_out, int out_size, void* d_ws, size_t ws_size,
                              hipStream_t stream) {
    const float* x   = (const float*)d_in[0];   // (T,B,2) fp32
    const float* raw = (const float*)d_in[1];   // (B,34)  fp32
    float* out = (float*)d_out;                 // (T,B,6) fp32

    const size_t need = (size_t)NLANES * TPAD * 2 * sizeof(float);  // 47.1 MB
    if (ws_size >= need) {
        float* snp = (float*)d_ws;
        float* gnp = snp + (size_t)NLANES * TPAD;
        scan_state<<<dim3(NLANES / 64), dim3(64),  0, stream>>>(x, raw, snp, gnp);
        finalize  <<<dim3(3, NB),       dim3(256), 0, stream>>>(x, raw, snp, gnp, out);
    } else {
        float* qs = (float*)d_ws;
        float* qg = qs + (size_t)T_STEPS * NB;
        float* uh = qg + (size_t)T_STEPS * NB;
        float* dm = uh + (size_t)LENF * NB;
        uh_fb  <<<dim3((NB + 255) / 256),          dim3(256), 0, stream>>>(raw, uh);
        scan_fb<<<dim3(NB / 8),                    dim3(64),  0, stream>>>(x, raw, out, qs, qg, dm);
        conv_fb<<<dim3((NB + 255) / 256, T_STEPS), dim3(256), 0, stream>>>(qs, qg, uh, out);
    }
}